// Round 5
// baseline (320.918 us; speedup 1.0000x reference)
//
#include <hip/hip_runtime.h>
#include <stdint.h>

typedef __bf16 bf16_t;
typedef __attribute__((ext_vector_type(8))) __bf16 bf16x8;
typedef __attribute__((ext_vector_type(4))) float f32x4;

#define NDIM 4096

// ---------------------------------------------------------------------------
// BFP quantize (unchanged)
// ---------------------------------------------------------------------------
__global__ __launch_bounds__(256) void quant_bfp(const float* __restrict__ in0,
                                                 bf16_t* __restrict__ out0,
                                                 const float* __restrict__ in1,
                                                 bf16_t* __restrict__ out1) {
    const float* in = blockIdx.y ? in1 : in0;
    bf16_t* out     = blockIdx.y ? out1 : out0;
    const int stride = gridDim.x * 256;
    for (int t = blockIdx.x * 256 + threadIdx.x; t < NDIM * NDIM / 4; t += stride) {
        float4 v = ((const float4*)in)[t];
        float m = fmaxf(fmaxf(fabsf(v.x), fabsf(v.y)), fmaxf(fabsf(v.z), fabsf(v.w)));
        m = fmaxf(m, __shfl_xor(m, 1));
        m = fmaxf(m, __shfl_xor(m, 2));
        m = fmaxf(m, __shfl_xor(m, 4));
        m = fmaxf(m, __shfl_xor(m, 8));
        const int e = (int)((__float_as_uint(m) >> 23) & 0xFF) - 127;
        float step = __uint_as_float((uint32_t)(e + 120) << 23);  // 2^(e-7)
        float inv  = __uint_as_float((uint32_t)(134 - e) << 23);  // 2^(7-e)
        if (m == 0.0f) { step = 0.0f; inv = 0.0f; }
        float q0 = fminf(fmaxf(rintf(v.x * inv), -128.0f), 127.0f) * step;
        float q1 = fminf(fmaxf(rintf(v.y * inv), -128.0f), 127.0f) * step;
        float q2 = fminf(fmaxf(rintf(v.z * inv), -128.0f), 127.0f) * step;
        float q3 = fminf(fmaxf(rintf(v.w * inv), -128.0f), 127.0f) * step;
        union { bf16_t b[4]; uint2 u; } o;
        o.b[0] = (bf16_t)q0; o.b[1] = (bf16_t)q1;
        o.b[2] = (bf16_t)q2; o.b[3] = (bf16_t)q3;
        ((uint2*)out)[t] = o.u;
    }
}

// ---------------------------------------------------------------------------
// GEMM round-5: REGISTER-PIPELINED fragments (read tile t+1's frags while
// MFMA'ing tile t). Counter-validated model: old iter = LDS(4608) + MFMA
// (4966) cyc, perfectly SERIAL because every phase's MFMA waits on that
// phase's ds_reads. Decoupling needs spare VGPRs -> shrink wave tile to
// 64x64 (acc 64 regs): block 256x128, 8 waves (4Mx2N), BK=64, LDS 96KB,
// frag cur+next in regs (~128), grid 512 = 2 clean rounds/CU.
// Per K-tile t (even halves shown; odd symmetric, static E/O regs):
//   LGKM0          ; my frag-reads of buf[t&1] (issued last half) complete
//   BAR            ; => ALL waves' reads of buf[t&1] complete (WAR gate)
//   STAGE(t+2)->buf[t&1]   ; 6 global_load_lds
//   WAITV(6)       ; my stage(t+1) loads done (ledger: 6 old + 6 new -> 6)
//   BAR            ; => ALL stage(t+1) loads done (RAW gate)
//   READS(next <- buf[(t+1)&1])  ; 16 ds_read_b128, no consumer this half
//   MFMA(cur) x32  ; ZERO lgkm dependency -> overlaps the ds_reads
// Tail (t+2>=64): dummy re-stage of k=0 -- REQUIRED to keep the vmcnt
// ledger uniform (skipping would let WAITV(6) pass with stage(63) pending).
// Final READS loads garbage that is never consumed (no MFMA follows).
// ---------------------------------------------------------------------------
__device__ __forceinline__ void g2l16(const bf16_t* g, void* l) {
    __builtin_amdgcn_global_load_lds(
        (__attribute__((address_space(1))) void*)g,
        (__attribute__((address_space(3))) void*)l, 16, 0, 0);
}

#define FENCE() asm volatile("" ::: "memory")
#define BAR()   do { FENCE(); __builtin_amdgcn_sched_barrier(0);              \
                     __builtin_amdgcn_s_barrier();                            \
                     __builtin_amdgcn_sched_barrier(0); FENCE(); } while (0)
#define WAITV(n) asm volatile("s_waitcnt vmcnt(" #n ")" ::: "memory")
#define LGKM0()  asm volatile("s_waitcnt lgkmcnt(0)" ::: "memory")

// stage one full K-tile (A 256x64 + B 128x64) into buffer bf: 6 loads/thread
#define STAGE(bf, koff) do {                                                    \
    _Pragma("unroll")                                                           \
    for (int i_ = 0; i_ < 4; ++i_)                                              \
        g2l16(gA + (size_t)(i_ * 64) * NDIM + (koff),                           \
              (char*)sA + (bf) * 32768 + i_ * 8192 + tid * 16);                 \
    _Pragma("unroll")                                                           \
    for (int j_ = 0; j_ < 2; ++j_)                                              \
        g2l16(gB + (size_t)(j_ * 64) * NDIM + (koff),                           \
              (char*)sB + (bf) * 16384 + j_ * 8192 + tid * 16);                 \
} while (0)

// load this wave's 64x64-tile fragments for one K-tile: 16 ds_read_b128
#define READS(fa, fb, bf) do {                                                  \
    _Pragma("unroll")                                                           \
    for (int i_ = 0; i_ < 4; ++i_) {                                            \
        const int r_ = (bf) * 16384 + aRow + i_ * 1024;                         \
        fa[i_][0] = *(const bf16x8*)&sA[r_ + ce0];                              \
        fa[i_][1] = *(const bf16x8*)&sA[r_ + ce1];                              \
    }                                                                           \
    _Pragma("unroll")                                                           \
    for (int j_ = 0; j_ < 4; ++j_) {                                            \
        const int r_ = (bf) * 8192 + bRow + j_ * 1024;                          \
        fb[j_][0] = *(const bf16x8*)&sB[r_ + ce0];                              \
        fb[j_][1] = *(const bf16x8*)&sB[r_ + ce1];                              \
    }                                                                           \
} while (0)

// one K-tile of MFMA: 4x4 frags x 2 k-slices = 32, prio-boosted
#define MFMAT(fa, fb) do {                                                      \
    __builtin_amdgcn_s_setprio(1);                                              \
    _Pragma("unroll")                                                           \
    for (int i_ = 0; i_ < 4; ++i_)                                              \
        _Pragma("unroll")                                                       \
        for (int j_ = 0; j_ < 4; ++j_) {                                        \
            acc[i_][j_] = __builtin_amdgcn_mfma_f32_16x16x32_bf16(              \
                fa[i_][0], fb[j_][0], acc[i_][j_], 0, 0, 0);                    \
            acc[i_][j_] = __builtin_amdgcn_mfma_f32_16x16x32_bf16(              \
                fa[i_][1], fb[j_][1], acc[i_][j_], 0, 0, 0);                    \
        }                                                                       \
    __builtin_amdgcn_s_setprio(0);                                              \
} while (0)

__global__ __launch_bounds__(512, 2) void gemm_bfp(const bf16_t* __restrict__ A,
                                                   const bf16_t* __restrict__ B,
                                                   const float* __restrict__ bias,
                                                   float* __restrict__ C) {
    __shared__ bf16_t sA[2 * 256 * 64];   // 64 KiB: [buf][row 0..255][k 0..63]
    __shared__ bf16_t sB[2 * 128 * 64];   // 32 KiB: [buf][row 0..127][k 0..63]

    const int tid  = threadIdx.x;
    const int wave = tid >> 6;
    const int lane = tid & 63;
    const int wm   = wave >> 1;           // 0..3  (M)
    const int wn   = wave & 1;            // 0..1  (N)

    // XCD-chunked remap: 512 blocks, XCD x owns wg [64x, 64x+64) = 2 bm rows
    const int p  = blockIdx.x;
    const int wg = (p & 7) * 64 + (p >> 3);
    const int bm = wg >> 5;               // 0..15 (256-row A panels)
    const int bn = wg & 31;               // 0..31 (128-col B panels)

    // staging geometry: thread -> (srow = tid>>3, chunk = tid&7), XOR-swz src
    const int srow = tid >> 3;            // 0..63
    const int swz  = ((tid & 7) ^ (srow & 7)) * 8;
    const bf16_t* gA = A + (size_t)(bm * 256 + srow) * NDIM + swz;
    const bf16_t* gB = B + (size_t)(bn * 128 + srow) * NDIM + swz;

    // read-side geometry (slot & 7 == l16 & 7 -> same swizzle key as source)
    const int quad = lane >> 4;
    const int l16  = lane & 15;
    const int rsw  = l16 & 7;
    const int ce0  = (quad ^ rsw) * 8;        // k-chunk quad   (ks=0)
    const int ce1  = ((4 + quad) ^ rsw) * 8;  // k-chunk 4+quad (ks=32)
    const int aRow = (wm * 64 + l16) * 64;    // elem base of wave's A rows
    const int bRow = (wn * 64 + l16) * 64;

    f32x4 acc[4][4];
#pragma unroll
    for (int i = 0; i < 4; ++i)
#pragma unroll
        for (int j = 0; j < 4; ++j) acc[i][j] = (f32x4){0.0f, 0.0f, 0.0f, 0.0f};

    // two named fragment sets (static indexing only -- rule #20)
    bf16x8 fAe[4][2], fBe[4][2];   // even tiles
    bf16x8 fAo[4][2], fBo[4][2];   // odd tiles

    // prologue: stage tiles 0,1; complete tile 0; prefetch tile-0 frags
    STAGE(0, 0);
    STAGE(1, 64);
    WAITV(6);            // tile-0 stage complete (mine)
    BAR();               // everyone's
    READS(fAe, fBe, 0);  // tile-0 frags in flight

    for (int t = 0; t < 64; t += 2) {
        const int k2 = (t + 2 < 64) ? (t + 2) * 64 : 0;  // dummy at tail (ledger!)
        const int k3 = (t + 3 < 64) ? (t + 3) * 64 : 0;

        // ---- even half: compute tile t (buf0) ----
        LGKM0();             // my buf0 frag-reads landed
        BAR();               // all waves' -> buf0 safe to overwrite
        STAGE(0, k2);        // tile t+2
        WAITV(6);            // tile t+1 stage complete (6 old + 6 new -> 6)
        BAR();
        READS(fAo, fBo, 1);  // tile t+1 frags (no consumer this half)
        MFMAT(fAe, fBe);     // tile t (zero lgkm dependency)

        // ---- odd half: compute tile t+1 (buf1) ----
        LGKM0();
        BAR();
        STAGE(1, k3);        // tile t+3
        WAITV(6);            // tile t+2 stage complete
        BAR();
        READS(fAe, fBe, 0);  // tile t+2 frags (garbage at t=62; never used)
        MFMAT(fAo, fBo);     // tile t+1
    }

    // epilogue: C/D layout col = lane&15, row = quad*4 + reg  [m89-verified]
    const int row0 = bm * 256 + wm * 64 + quad * 4;
    const int col0 = bn * 128 + wn * 64 + l16;
#pragma unroll
    for (int nj = 0; nj < 4; ++nj) {
        const int c = col0 + nj * 16;
        const float bv = 2.0f * bias[c];
#pragma unroll
        for (int mi = 0; mi < 4; ++mi) {
            const int r = row0 + mi * 16;
#pragma unroll
            for (int reg = 0; reg < 4; ++reg)
                C[(size_t)(r + reg) * NDIM + c] = acc[mi][nj][reg] + bv;
        }
    }
}

extern "C" void kernel_launch(void* const* d_in, const int* in_sizes, int n_in,
                              void* d_out, int out_size, void* d_ws, size_t ws_size,
                              hipStream_t stream) {
    const float* x    = (const float*)d_in[0];
    const float* w    = (const float*)d_in[1];
    const float* bias = (const float*)d_in[2];
    float* out = (float*)d_out;

    bf16_t* xq = (bf16_t*)d_ws;                         // 32 MB
    bf16_t* wq = xq + (size_t)NDIM * NDIM;              // 32 MB

    dim3 qgrid(1024, 2);
    quant_bfp<<<qgrid, 256, 0, stream>>>(x, xq, w, wq);

    dim3 grid(512);                                     // 16 x 32 tiles, 2 rounds/CU
    gemm_bfp<<<grid, 512, 0, stream>>>(xq, wq, bias, out);
}

// Round 6
// 274.327 us; speedup vs baseline: 1.1698x; 1.1698x over previous
//
#include <hip/hip_runtime.h>
#include <stdint.h>

typedef __bf16 bf16_t;
typedef __attribute__((ext_vector_type(8))) __bf16 bf16x8;
typedef __attribute__((ext_vector_type(4))) float f32x4;

#define NDIM 4096
#define QHALF (NDIM * NDIM / 8)   // half the tensor, in float4 units (mult of 16)

// ---------------------------------------------------------------------------
// BFP quantize, round-6: 2x memory-level parallelism. Each iteration issues
// TWO independent float4 NT loads (t and t+QHALF; group alignment preserved
// since QHALF % 16 == 0), runs two independent 16-lane shuffle-max chains
// interleaved, stores two uint2. NT loads: x/w are single-use streams.
// ---------------------------------------------------------------------------
__global__ __launch_bounds__(256) void quant_bfp(const float* __restrict__ in0,
                                                 bf16_t* __restrict__ out0,
                                                 const float* __restrict__ in1,
                                                 bf16_t* __restrict__ out1) {
    const float* in = blockIdx.y ? in1 : in0;
    bf16_t* out     = blockIdx.y ? out1 : out0;
    const int stride = gridDim.x * 256;
    for (int t = blockIdx.x * 256 + threadIdx.x; t < QHALF; t += stride) {
        f32x4 va = __builtin_nontemporal_load((const f32x4*)in + t);
        f32x4 vb = __builtin_nontemporal_load((const f32x4*)in + t + QHALF);

        float ma = fmaxf(fmaxf(fabsf(va[0]), fabsf(va[1])),
                         fmaxf(fabsf(va[2]), fabsf(va[3])));
        float mb = fmaxf(fmaxf(fabsf(vb[0]), fabsf(vb[1])),
                         fmaxf(fabsf(vb[2]), fabsf(vb[3])));
        ma = fmaxf(ma, __shfl_xor(ma, 1));  mb = fmaxf(mb, __shfl_xor(mb, 1));
        ma = fmaxf(ma, __shfl_xor(ma, 2));  mb = fmaxf(mb, __shfl_xor(mb, 2));
        ma = fmaxf(ma, __shfl_xor(ma, 4));  mb = fmaxf(mb, __shfl_xor(mb, 4));
        ma = fmaxf(ma, __shfl_xor(ma, 8));  mb = fmaxf(mb, __shfl_xor(mb, 8));

        const int ea = (int)((__float_as_uint(ma) >> 23) & 0xFF) - 127;
        const int eb = (int)((__float_as_uint(mb) >> 23) & 0xFF) - 127;
        float stepa = __uint_as_float((uint32_t)(ea + 120) << 23);  // 2^(e-7)
        float inva  = __uint_as_float((uint32_t)(134 - ea) << 23);  // 2^(7-e)
        float stepb = __uint_as_float((uint32_t)(eb + 120) << 23);
        float invb  = __uint_as_float((uint32_t)(134 - eb) << 23);
        if (ma == 0.0f) { stepa = 0.0f; inva = 0.0f; }
        if (mb == 0.0f) { stepb = 0.0f; invb = 0.0f; }

        union { bf16_t b[4]; uint2 u; } oa, ob;
#pragma unroll
        for (int k = 0; k < 4; ++k) {
            oa.b[k] = (bf16_t)(fminf(fmaxf(rintf(va[k] * inva), -128.0f), 127.0f) * stepa);
            ob.b[k] = (bf16_t)(fminf(fmaxf(rintf(vb[k] * invb), -128.0f), 127.0f) * stepb);
        }
        ((uint2*)out)[t]         = oa.u;
        ((uint2*)out)[t + QHALF] = ob.u;
    }
}

// ---------------------------------------------------------------------------
// GEMM: EXACT round-4 kernel (best measured: 126.3 us, MfmaUtil 45.4%,
// 0 bank conflicts). 256x256 tile, quadrant-local LDS regions, one barrier
// per phase (8/iter), vmcnt(6) at p4/p8. See round-4 hazard proof.
// ---------------------------------------------------------------------------
__device__ __forceinline__ void g2l16(const bf16_t* g, void* l) {
    __builtin_amdgcn_global_load_lds(
        (__attribute__((address_space(1))) void*)g,
        (__attribute__((address_space(3))) void*)l, 16, 0, 0);
}

#define FENCE() asm volatile("" ::: "memory")
#define BAR()   do { FENCE(); __builtin_amdgcn_sched_barrier(0);              \
                     __builtin_amdgcn_s_barrier();                            \
                     __builtin_amdgcn_sched_barrier(0); FENCE(); } while (0)
#define WAITV(n) asm volatile("s_waitcnt vmcnt(" #n ")" ::: "memory")

#define STAGE_A(b, r, ko) do {                                                  \
    g2l16(gA + (size_t)((r) * 64) * NDIM + (ko),                                \
          (char*)sA + (b) * 32768 + (r) * 16384 + tid * 16);                    \
    g2l16(gA + (size_t)((r) * 64 + 128) * NDIM + (ko),                          \
          (char*)sA + (b) * 32768 + (r) * 16384 + 8192 + tid * 16);             \
} while (0)
#define STAGE_B(b, r, ko) do {                                                  \
    g2l16(gB + (size_t)((r) * 32) * NDIM + (ko),                                \
          (char*)sB + (b) * 32768 + (r) * 16384 + tid * 16);                    \
    g2l16(gB + (size_t)((r) * 32 + 128) * NDIM + (ko),                          \
          (char*)sB + (b) * 32768 + (r) * 16384 + 8192 + tid * 16);             \
} while (0)

#define LDA(b, qm) do {                                                         \
    _Pragma("unroll")                                                           \
    for (int i_ = 0; i_ < 4; ++i_) {                                            \
        const int r_ = (b) * 16384 + (qm) * 8192 + aRow + i_ * 1024;            \
        afr[i_][0] = *(const bf16x8*)&sA[r_ + ce0];                             \
        afr[i_][1] = *(const bf16x8*)&sA[r_ + ce1];                             \
    }                                                                           \
} while (0)
#define LDB(b, qn) do {                                                         \
    _Pragma("unroll")                                                           \
    for (int j_ = 0; j_ < 2; ++j_) {                                            \
        const int r_ = (b) * 16384 + (qn) * 8192 + bRow + j_ * 1024;            \
        bfr[qn][j_][0] = *(const bf16x8*)&sB[r_ + ce0];                         \
        bfr[qn][j_][1] = *(const bf16x8*)&sB[r_ + ce1];                         \
    }                                                                           \
} while (0)

#define MFMAQ(qm, qn) do {                                                      \
    __builtin_amdgcn_s_setprio(1);                                              \
    _Pragma("unroll")                                                           \
    for (int i_ = 0; i_ < 4; ++i_)                                              \
        _Pragma("unroll")                                                       \
        for (int j_ = 0; j_ < 2; ++j_) {                                        \
            acc[(qm)*4+i_][(qn)*2+j_] = __builtin_amdgcn_mfma_f32_16x16x32_bf16(\
                afr[i_][0], bfr[qn][j_][0], acc[(qm)*4+i_][(qn)*2+j_], 0, 0, 0);\
            acc[(qm)*4+i_][(qn)*2+j_] = __builtin_amdgcn_mfma_f32_16x16x32_bf16(\
                afr[i_][1], bfr[qn][j_][1], acc[(qm)*4+i_][(qn)*2+j_], 0, 0, 0);\
        }                                                                       \
    __builtin_amdgcn_s_setprio(0);                                              \
} while (0)

__global__ __launch_bounds__(512, 2) void gemm_bfp(const bf16_t* __restrict__ A,
                                                   const bf16_t* __restrict__ B,
                                                   const float* __restrict__ bias,
                                                   float* __restrict__ C) {
    __shared__ bf16_t sA[2 * 256 * 64];   // [buf][region][slot 0..127][k 0..63]
    __shared__ bf16_t sB[2 * 256 * 64];

    const int tid  = threadIdx.x;
    const int wave = tid >> 6;
    const int lane = tid & 63;
    const int wr   = wave >> 2;           // 0..1  (M)
    const int wc   = wave & 3;            // 0..3  (N)

    const int p  = blockIdx.x;
    const int wg = (p & 7) * 32 + (p >> 3);
    const int bm = wg >> 4;
    const int bn = wg & 15;

    const int srow = tid >> 3;
    const int swz  = ((tid & 7) ^ (srow & 7)) * 8;
    const bf16_t* gA = A + (size_t)(bm * 256 + srow) * NDIM + swz;
    const bf16_t* gB = B + (size_t)(bn * 256 + (srow >> 5) * 64 + (srow & 31)) * NDIM + swz;

    const int quad = lane >> 4;
    const int l16  = lane & 15;
    const int rsw  = l16 & 7;
    const int ce0  = (quad ^ rsw) * 8;        // global k-chunk quad   (ks=0)
    const int ce1  = ((4 + quad) ^ rsw) * 8;  // global k-chunk 4+quad (ks=32)
    const int aRow = (wr * 64 + l16) * 64;
    const int bRow = (wc * 32 + l16) * 64;

    f32x4 acc[8][4];
#pragma unroll
    for (int i = 0; i < 8; ++i)
#pragma unroll
        for (int j = 0; j < 4; ++j) acc[i][j] = (f32x4){0.0f, 0.0f, 0.0f, 0.0f};

    bf16x8 afr[4][2];
    bf16x8 bfr[2][2][2];

    STAGE_A(0, 0, 0); STAGE_B(0, 0, 0); STAGE_B(0, 1, 0); STAGE_A(0, 1, 0);
    STAGE_A(1, 0, 64); STAGE_B(1, 0, 64); STAGE_B(1, 1, 64);
    WAITV(6);

    for (int kt = 0; kt < NDIM; kt += 128) {
        const int koA1 = kt + 64;
        const int koN2 = (kt + 128 < NDIM) ? kt + 128 : 0;
        const int koB3 = (kt + 192 < NDIM) ? kt + 192 : 0;

        // p1: reads A(0,r0)+B(0,r0); stages A(1,r1)
        BAR();
        LDA(0, 0); LDB(0, 0);
        STAGE_A(1, 1, koA1);
        MFMAQ(0, 0);

        // p2: reads B(0,r1); stages A(0,r0)
        BAR();
        LDB(0, 1);
        STAGE_A(0, 0, koN2);
        MFMAQ(0, 1);

        // p3: reads A(0,r1); stages B(0,r0)
        BAR();
        LDA(0, 1);
        STAGE_B(0, 0, koN2);
        MFMAQ(1, 1);

        // p4: stages B(0,r1); vmcnt completes A10',B10',B11',A11
        BAR();
        STAGE_B(0, 1, koN2);
        MFMAQ(1, 0);
        WAITV(6);

        // p5: reads A(1,r0)+B(1,r0); stages A(0,r1)
        BAR();
        LDA(1, 0); LDB(1, 0);
        STAGE_A(0, 1, koN2);
        MFMAQ(0, 0);

        // p6: reads B(1,r1); stages A(1,r0)
        BAR();
        LDB(1, 1);
        STAGE_A(1, 0, koB3);
        MFMAQ(0, 1);

        // p7: reads A(1,r1); stages B(1,r0)
        BAR();
        LDA(1, 1);
        STAGE_B(1, 0, koB3);
        MFMAQ(1, 1);

        // p8: stages B(1,r1); vmcnt completes A00,B00,B01,A01
        BAR();
        STAGE_B(1, 1, koB3);
        MFMAQ(1, 0);
        WAITV(6);
    }

    const int row0 = bm * 256 + wr * 128 + quad * 4;
    const int col0 = bn * 256 + wc * 64 + l16;
#pragma unroll
    for (int nj = 0; nj < 4; ++nj) {
        const int c = col0 + nj * 16;
        const float bv = 2.0f * bias[c];
#pragma unroll
        for (int mi = 0; mi < 8; ++mi) {
            const int r = row0 + mi * 16;
#pragma unroll
            for (int reg = 0; reg < 4; ++reg)
                C[(size_t)(r + reg) * NDIM + c] = acc[mi][nj][reg] + bv;
        }
    }
}

extern "C" void kernel_launch(void* const* d_in, const int* in_sizes, int n_in,
                              void* d_out, int out_size, void* d_ws, size_t ws_size,
                              hipStream_t stream) {
    const float* x    = (const float*)d_in[0];
    const float* w    = (const float*)d_in[1];
    const float* bias = (const float*)d_in[2];
    float* out = (float*)d_out;

    bf16_t* xq = (bf16_t*)d_ws;                         // 32 MB
    bf16_t* wq = xq + (size_t)NDIM * NDIM;              // 32 MB

    dim3 qgrid(1024, 2);                                // 8 iters/thread, 2x MLP
    quant_bfp<<<qgrid, 256, 0, stream>>>(x, xq, w, wq);

    dim3 grid(256);
    gemm_bfp<<<grid, 512, 0, stream>>>(xq, wq, bias, out);
}